// Round 2
// baseline (76.821 us; speedup 1.0000x reference)
//
#include <hip/hip_runtime.h>
#include <cstdint>
#include <cstddef>

#define ROWS 16384
#define COLS 1024

__device__ __forceinline__ uint32_t rotl32(uint32_t x, int r) {
    return (x << r) | (x >> (32 - r));
}

__device__ __forceinline__ void tf_round(uint32_t& x0, uint32_t& x1, int r) {
    x0 += x1;
    x1 = rotl32(x1, r);
    x1 ^= x0;
}

// Threefry-2x32-20 with key (0, 42) == jax.random.key(42).
// Verified against Random123 KAT (key 0,0 ctr 0,0 -> 6b200159 99ba4efe).
__device__ __forceinline__ void threefry_0_42(uint32_t c0, uint32_t c1,
                                              uint32_t& o0, uint32_t& o1) {
    const uint32_t ks0 = 0u;
    const uint32_t ks1 = 42u;
    const uint32_t ks2 = 0x1BD11BDAu ^ 0u ^ 42u;

    uint32_t x0 = c0 + ks0;
    uint32_t x1 = c1 + ks1;

    // group 0: rotations {13,15,26,6}
    tf_round(x0, x1, 13); tf_round(x0, x1, 15); tf_round(x0, x1, 26); tf_round(x0, x1, 6);
    x0 += ks1; x1 += ks2 + 1u;
    // group 1: rotations {17,29,16,24}
    tf_round(x0, x1, 17); tf_round(x0, x1, 29); tf_round(x0, x1, 16); tf_round(x0, x1, 24);
    x0 += ks2; x1 += ks0 + 2u;
    // group 2
    tf_round(x0, x1, 13); tf_round(x0, x1, 15); tf_round(x0, x1, 26); tf_round(x0, x1, 6);
    x0 += ks0; x1 += ks1 + 3u;
    // group 3
    tf_round(x0, x1, 17); tf_round(x0, x1, 29); tf_round(x0, x1, 16); tf_round(x0, x1, 24);
    x0 += ks1; x1 += ks2 + 4u;
    // group 4
    tf_round(x0, x1, 13); tf_round(x0, x1, 15); tf_round(x0, x1, 26); tf_round(x0, x1, 6);
    x0 += ks2; x1 += ks0 + 5u;

    o0 = x0; o1 = x1;
}

// XLA ErfInv32 (Giles): w = -log1p(-x^2); two polynomial branches.
__device__ __forceinline__ float erfinv_xla(float x) {
    float w = -log1pf(-x * x);
    float p;
    if (w < 5.0f) {
        w -= 2.5f;
        p = 2.81022636e-08f;
        p = fmaf(p, w, 3.43273939e-07f);
        p = fmaf(p, w, -3.5233877e-06f);
        p = fmaf(p, w, -4.39150654e-06f);
        p = fmaf(p, w, 0.00021858087f);
        p = fmaf(p, w, -0.00125372503f);
        p = fmaf(p, w, -0.00417768164f);
        p = fmaf(p, w, 0.246640727f);
        p = fmaf(p, w, 1.50140941f);
    } else {
        w = sqrtf(w) - 3.0f;
        p = -0.000200214257f;
        p = fmaf(p, w, 0.000100950558f);
        p = fmaf(p, w, 0.00134934322f);
        p = fmaf(p, w, -0.00367342844f);
        p = fmaf(p, w, 0.00573950773f);
        p = fmaf(p, w, -0.0076224613f);
        p = fmaf(p, w, 0.00943887047f);
        p = fmaf(p, w, 1.00167406f);
        p = fmaf(p, w, 2.83297682f);
    }
    return p * x;
}

// bits -> jax uniform(-0.99999994, 1.0) -> sqrt(2)*erfinv -> *1.1
__device__ __forceinline__ float bits_to_noise(uint32_t bits) {
    uint32_t fb = (bits >> 9) | 0x3f800000u;
    float u = __uint_as_float(fb) - 1.0f;            // [0, 1)
    const float minval = -0.99999994f;               // nextafter(-1, 0) in f32
    float v = fmaf(u, 2.0f, minval);                 // u*2 exact -> identical to mul+add
    v = fmaxf(v, minval);
    const float sqrt2 = 1.41421356f;                 // 0x3FB504F3 = f32(sqrt(2))
    return 1.1f * (sqrt2 * erfinv_xla(v));
}

// One block per row; 256 threads x float4.
// Partitionable threefry: element flat index i -> counter (hi,lo)=(0,i),
// bits = o0 ^ o1.
__global__ void __launch_bounds__(256)
gaussian_dp_kernel(const float* __restrict__ in, float* __restrict__ out) {
    const int r    = blockIdx.x;       // 0..16383
    const int tid  = threadIdx.x;      // 0..255
    const int lane = tid & 63;
    const int wid  = tid >> 6;

    const float4* inR = reinterpret_cast<const float4*>(in + (size_t)r * COLS);
    float4 a = inR[tid];

    float ssq = fmaf(a.x, a.x, fmaf(a.y, a.y, fmaf(a.z, a.z, a.w * a.w)));

    #pragma unroll
    for (int off = 32; off > 0; off >>= 1) {
        ssq += __shfl_down(ssq, off, 64);
    }

    __shared__ float s[4];
    if (lane == 0) s[wid] = ssq;
    __syncthreads();

    const float tot = (s[0] + s[1]) + (s[2] + s[3]);
    const float scale = 1.0f / fmaxf(sqrtf(tot), 1.0f);

    const uint32_t base = (uint32_t)r * (uint32_t)COLS + (uint32_t)tid * 4u;

    float n[4];
    #pragma unroll
    for (int k = 0; k < 4; ++k) {
        uint32_t o0, o1;
        threefry_0_42(0u, base + (uint32_t)k, o0, o1);
        n[k] = bits_to_noise(o0 ^ o1);
    }

    float4 o;
    o.x = fmaf(a.x, scale, n[0]);
    o.y = fmaf(a.y, scale, n[1]);
    o.z = fmaf(a.z, scale, n[2]);
    o.w = fmaf(a.w, scale, n[3]);

    float4* outR = reinterpret_cast<float4*>(out + (size_t)r * COLS);
    outR[tid] = o;
}

extern "C" void kernel_launch(void* const* d_in, const int* in_sizes, int n_in,
                              void* d_out, int out_size, void* d_ws, size_t ws_size,
                              hipStream_t stream) {
    const float* in = (const float*)d_in[0];
    float* out = (float*)d_out;
    gaussian_dp_kernel<<<ROWS, 256, 0, stream>>>(in, out);
}

// Round 3
// 43.502 us; speedup vs baseline: 1.7659x; 1.7659x over previous
//
#include <hip/hip_runtime.h>
#include <cstdint>
#include <cstddef>

#define ROWS 16384
#define COLS 1024

// rotl via single v_alignbit_b32: alignbit(x,x,32-r) = (x>>(32-r))|(x<<r)
__device__ __forceinline__ uint32_t rotl32(uint32_t x, int r) {
    return __builtin_amdgcn_alignbit(x, x, 32 - r);
}

__device__ __forceinline__ void tf_round(uint32_t& x0, uint32_t& x1, int r) {
    x0 += x1;
    x1 = rotl32(x1, r);
    x1 ^= x0;
}

// Threefry-2x32-20 with key (0, 42) == jax.random.key(42).
__device__ __forceinline__ void threefry_0_42(uint32_t c0, uint32_t c1,
                                              uint32_t& o0, uint32_t& o1) {
    const uint32_t ks0 = 0u;
    const uint32_t ks1 = 42u;
    const uint32_t ks2 = 0x1BD11BDAu ^ 0u ^ 42u;

    uint32_t x0 = c0 + ks0;
    uint32_t x1 = c1 + ks1;

    tf_round(x0, x1, 13); tf_round(x0, x1, 15); tf_round(x0, x1, 26); tf_round(x0, x1, 6);
    x0 += ks1; x1 += ks2 + 1u;
    tf_round(x0, x1, 17); tf_round(x0, x1, 29); tf_round(x0, x1, 16); tf_round(x0, x1, 24);
    x0 += ks2; x1 += ks0 + 2u;
    tf_round(x0, x1, 13); tf_round(x0, x1, 15); tf_round(x0, x1, 26); tf_round(x0, x1, 6);
    x0 += ks0; x1 += ks1 + 3u;
    tf_round(x0, x1, 17); tf_round(x0, x1, 29); tf_round(x0, x1, 16); tf_round(x0, x1, 24);
    x0 += ks1; x1 += ks2 + 4u;
    tf_round(x0, x1, 13); tf_round(x0, x1, 15); tf_round(x0, x1, 26); tf_round(x0, x1, 6);
    x0 += ks2; x1 += ks0 + 5u;

    o0 = x0; o1 = x1;
}

// XLA ErfInv32 (Giles) with hardware log2 instead of software log1pf.
// w = -log1p(-x^2) == -ln(1-x^2); fma(-x,x,1) keeps the cancellation exact
// enough (one rounding), hw v_log_f32 is ~1 ulp; absmax budget is 0.12.
__device__ __forceinline__ float erfinv_fast(float x) {
    float t = fmaf(-x, x, 1.0f);                 // 1 - x^2, single rounding
    float w = -0.69314718f * __log2f(t);         // -ln(1-x^2)
    float p;
    if (w < 5.0f) {
        w -= 2.5f;
        p = 2.81022636e-08f;
        p = fmaf(p, w, 3.43273939e-07f);
        p = fmaf(p, w, -3.5233877e-06f);
        p = fmaf(p, w, -4.39150654e-06f);
        p = fmaf(p, w, 0.00021858087f);
        p = fmaf(p, w, -0.00125372503f);
        p = fmaf(p, w, -0.00417768164f);
        p = fmaf(p, w, 0.246640727f);
        p = fmaf(p, w, 1.50140941f);
    } else {
        w = sqrtf(w) - 3.0f;
        p = -0.000200214257f;
        p = fmaf(p, w, 0.000100950558f);
        p = fmaf(p, w, 0.00134934322f);
        p = fmaf(p, w, -0.00367342844f);
        p = fmaf(p, w, 0.00573950773f);
        p = fmaf(p, w, -0.0076224613f);
        p = fmaf(p, w, 0.00943887047f);
        p = fmaf(p, w, 1.00167406f);
        p = fmaf(p, w, 2.83297682f);
    }
    return p * x;
}

// bits -> jax uniform(-0.99999994, 1.0) -> sqrt(2)*erfinv -> *1.1
__device__ __forceinline__ float bits_to_noise(uint32_t bits) {
    uint32_t fb = (bits >> 9) | 0x3f800000u;
    float u = __uint_as_float(fb) - 1.0f;        // [0, 1)
    const float minval = -0.99999994f;
    float v = fmaf(u, 2.0f, minval);
    v = fmaxf(v, minval);
    const float sqrt2 = 1.41421356f;
    return 1.1f * (sqrt2 * erfinv_fast(v));
}

__device__ __forceinline__ float4 noise4(uint32_t idx0) {
    float4 n;
    uint32_t o0, o1;
    threefry_0_42(0u, idx0 + 0u, o0, o1); n.x = bits_to_noise(o0 ^ o1);
    threefry_0_42(0u, idx0 + 1u, o0, o1); n.y = bits_to_noise(o0 ^ o1);
    threefry_0_42(0u, idx0 + 2u, o0, o1); n.z = bits_to_noise(o0 ^ o1);
    threefry_0_42(0u, idx0 + 3u, o0, o1); n.w = bits_to_noise(o0 ^ o1);
    return n;
}

__device__ __forceinline__ float ssq4(float4 a) {
    return fmaf(a.x, a.x, fmaf(a.y, a.y, fmaf(a.z, a.z, a.w * a.w)));
}

// One WAVE per row (64 lanes x 16 elems); 4 rows per 256-thread block.
// No LDS, no __syncthreads — pure shfl_xor reduce.
__global__ void __launch_bounds__(256)
gaussian_dp_kernel(const float* __restrict__ in, float* __restrict__ out) {
    const int wid  = threadIdx.x >> 6;
    const int lane = threadIdx.x & 63;
    const int r    = (blockIdx.x << 2) + wid;   // 0..16383

    const float4* inR = reinterpret_cast<const float4*>(in + (size_t)r * COLS);
    float4 a0 = inR[lane];
    float4 a1 = inR[lane + 64];
    float4 a2 = inR[lane + 128];
    float4 a3 = inR[lane + 192];

    float ssq = (ssq4(a0) + ssq4(a1)) + (ssq4(a2) + ssq4(a3));

    #pragma unroll
    for (int off = 32; off > 0; off >>= 1) {
        ssq += __shfl_xor(ssq, off, 64);
    }

    const float scale = 1.0f / fmaxf(sqrtf(ssq), 1.0f);

    // flat element index of this thread's first element in group k:
    // idx = r*1024 + (lane + k*64)*4
    const uint32_t base = ((uint32_t)r << 10) + ((uint32_t)lane << 2);

    float4* outR = reinterpret_cast<float4*>(out + (size_t)r * COLS);

    {
        float4 n = noise4(base);
        float4 o;
        o.x = fmaf(a0.x, scale, n.x); o.y = fmaf(a0.y, scale, n.y);
        o.z = fmaf(a0.z, scale, n.z); o.w = fmaf(a0.w, scale, n.w);
        outR[lane] = o;
    }
    {
        float4 n = noise4(base + 256u);
        float4 o;
        o.x = fmaf(a1.x, scale, n.x); o.y = fmaf(a1.y, scale, n.y);
        o.z = fmaf(a1.z, scale, n.z); o.w = fmaf(a1.w, scale, n.w);
        outR[lane + 64] = o;
    }
    {
        float4 n = noise4(base + 512u);
        float4 o;
        o.x = fmaf(a2.x, scale, n.x); o.y = fmaf(a2.y, scale, n.y);
        o.z = fmaf(a2.z, scale, n.z); o.w = fmaf(a2.w, scale, n.w);
        outR[lane + 128] = o;
    }
    {
        float4 n = noise4(base + 768u);
        float4 o;
        o.x = fmaf(a3.x, scale, n.x); o.y = fmaf(a3.y, scale, n.y);
        o.z = fmaf(a3.z, scale, n.z); o.w = fmaf(a3.w, scale, n.w);
        outR[lane + 192] = o;
    }
}

extern "C" void kernel_launch(void* const* d_in, const int* in_sizes, int n_in,
                              void* d_out, int out_size, void* d_ws, size_t ws_size,
                              hipStream_t stream) {
    const float* in = (const float*)d_in[0];
    float* out = (float*)d_out;
    gaussian_dp_kernel<<<ROWS / 4, 256, 0, stream>>>(in, out);
}

// Round 5
// 42.614 us; speedup vs baseline: 1.8027x; 1.0208x over previous
//
#include <hip/hip_runtime.h>
#include <cstdint>
#include <cstddef>

#define ROWS 16384
#define COLS 1024

// rotl via single v_alignbit_b32: alignbit(x,x,32-r) = (x>>(32-r))|(x<<r)
__device__ __forceinline__ uint32_t rotl32(uint32_t x, int r) {
    return __builtin_amdgcn_alignbit(x, x, 32 - r);
}

__device__ __forceinline__ void tf_round(uint32_t& x0, uint32_t& x1, int r) {
    x0 += x1;
    x1 = rotl32(x1, r);
    x1 ^= x0;
}

// Threefry-2x32-20, key (0,42) == jax.random.key(42), counter (0, i),
// specialized for c0 == 0 (partitionable threefry, bits = o0 ^ o1).
__device__ __forceinline__ uint32_t threefry_bits(uint32_t i) {
    const uint32_t ks1 = 42u;
    const uint32_t ks2 = 0x1BD11BF0u;   // 0x1BD11BDA ^ 0 ^ 42

    uint32_t x1 = i + 42u;
    uint32_t x0 = x1;                    // R1: x0 = 0 + x1
    x1 = rotl32(x1, 13) ^ x0;
    tf_round(x0, x1, 15); tf_round(x0, x1, 26); tf_round(x0, x1, 6);
    x0 += ks1; x1 += ks2 + 1u;
    tf_round(x0, x1, 17); tf_round(x0, x1, 29); tf_round(x0, x1, 16); tf_round(x0, x1, 24);
    x0 += ks2; x1 += 2u;                 // ks0 == 0
    tf_round(x0, x1, 13); tf_round(x0, x1, 15); tf_round(x0, x1, 26); tf_round(x0, x1, 6);
    /* x0 += 0 */ x1 += ks1 + 3u;
    tf_round(x0, x1, 17); tf_round(x0, x1, 29); tf_round(x0, x1, 16); tf_round(x0, x1, 24);
    x0 += ks1; x1 += ks2 + 4u;
    tf_round(x0, x1, 13); tf_round(x0, x1, 15); tf_round(x0, x1, 26); tf_round(x0, x1, 6);
    x0 += ks2; x1 += 5u;                 // ks0 == 0
    return x0 ^ x1;
}

__device__ __forceinline__ float ssq4(float4 a) {
    return fmaf(a.x, a.x, fmaf(a.y, a.y, fmaf(a.z, a.z, a.w * a.w)));
}

// Coefficient bundle: XLA ErfInv32 (Giles) coefficients pre-scaled by
// 1.1*sqrt(2) = 1.5556349186, pinned into SGPRs so each Horner step is a
// single v_fma_f32 (VOP3 can read 1 SGPR but not a 32-bit literal).
struct ErfC {
    float k0,k1,k2,k3,k4,k5,k6,k7,k8, ln2;
};

__device__ __forceinline__ ErfC make_coefs() {
    ErfC c;
    c.k0 = 4.3716863e-08f;
    c.k1 = 5.3400890e-07f;
    c.k2 = -5.4811046e-06f;
    c.k3 = -6.8315807e-06f;
    c.k4 = 3.4003203e-04f;
    c.k5 = -1.9503385e-03f;
    c.k6 = -6.4989473e-03f;
    c.k7 = 3.8368293e-01f;
    c.k8 = 2.3356449e+00f;
    c.ln2 = 0.69314718f;
    asm("" : "+s"(c.k0), "+s"(c.k1), "+s"(c.k2), "+s"(c.k3), "+s"(c.k4),
             "+s"(c.k5), "+s"(c.k6), "+s"(c.k7), "+s"(c.k8), "+s"(c.ln2));
    return c;
}

// bits -> jax uniform(-0.99999994, 1) -> 1.1*sqrt(2)*erfinv (scale folded in)
__device__ __forceinline__ float bits_to_noise(uint32_t bits, const ErfC& c) {
    uint32_t fb = (bits >> 9) | 0x3f800000u;
    float u = __uint_as_float(fb) - 1.0f;        // [0,1), exact (Sterbenz)
    const float minval = -0.99999994f;
    float v = fmaf(u, 2.0f, minval);             // == jax mul+add; >= minval always
    float t = fmaf(-v, v, 1.0f);                 // 1 - v^2, single rounding
    float w = -c.ln2 * __log2f(t);               // -ln(1-v^2)

    float z = w - 2.5f;
    float p = c.k0;
    p = fmaf(p, z, c.k1);
    p = fmaf(p, z, c.k2);
    p = fmaf(p, z, c.k3);
    p = fmaf(p, z, c.k4);
    p = fmaf(p, z, c.k5);
    p = fmaf(p, z, c.k6);
    p = fmaf(p, z, c.k7);
    p = fmaf(p, z, c.k8);

    if (w >= 5.0f) {                             // rare: |v| > 0.99665 (~0.33%/lane)
        float s = __builtin_amdgcn_sqrtf(w) - 3.0f;
        float q = -3.1146030e-04f;
        q = fmaf(q, s, 1.5704224e-04f);
        q = fmaf(q, s, 2.0990855e-03f);
        q = fmaf(q, s, -5.7144932e-03f);
        q = fmaf(q, s, 8.9285939e-03f);
        q = fmaf(q, s, -1.1857797e-02f);
        q = fmaf(q, s, 1.4683435e-02f);
        q = fmaf(q, s, 1.5582439e+00f);
        q = fmaf(q, s, 4.4070777e+00f);
        p = q;
    }
    return p * v;                                // noise = 1.1*sqrt2*erfinv(v)
}

__device__ __forceinline__ float4 noise4(uint32_t idx0, const ErfC& c) {
    float4 n;
    n.x = bits_to_noise(threefry_bits(idx0 + 0u), c);
    n.y = bits_to_noise(threefry_bits(idx0 + 1u), c);
    n.z = bits_to_noise(threefry_bits(idx0 + 2u), c);
    n.w = bits_to_noise(threefry_bits(idx0 + 3u), c);
    return n;
}

// One WAVE per row (64 lanes x 16 elems); 4 rows per 256-thread block.
// No LDS, no __syncthreads — pure shfl_xor reduce.
__global__ void __launch_bounds__(256)
gaussian_dp_kernel(const float* __restrict__ in, float* __restrict__ out) {
    const int wid  = threadIdx.x >> 6;
    const int lane = threadIdx.x & 63;
    const int r    = (blockIdx.x << 2) + wid;   // 0..16383

    const float4* inR = reinterpret_cast<const float4*>(in + (size_t)r * COLS);
    float4 a0 = inR[lane];
    float4 a1 = inR[lane + 64];
    float4 a2 = inR[lane + 128];
    float4 a3 = inR[lane + 192];

    float ssq = (ssq4(a0) + ssq4(a1)) + (ssq4(a2) + ssq4(a3));

    #pragma unroll
    for (int off = 32; off > 0; off >>= 1) {
        ssq += __shfl_xor(ssq, off, 64);
    }

    const float scale = 1.0f / fmaxf(sqrtf(ssq), 1.0f);

    const ErfC c = make_coefs();

    const uint32_t base = ((uint32_t)r << 10) + ((uint32_t)lane << 2);

    float4* outR = reinterpret_cast<float4*>(out + (size_t)r * COLS);

    {
        float4 n = noise4(base, c);
        float4 o;
        o.x = fmaf(a0.x, scale, n.x); o.y = fmaf(a0.y, scale, n.y);
        o.z = fmaf(a0.z, scale, n.z); o.w = fmaf(a0.w, scale, n.w);
        outR[lane] = o;
    }
    {
        float4 n = noise4(base + 256u, c);
        float4 o;
        o.x = fmaf(a1.x, scale, n.x); o.y = fmaf(a1.y, scale, n.y);
        o.z = fmaf(a1.z, scale, n.z); o.w = fmaf(a1.w, scale, n.w);
        outR[lane + 64] = o;
    }
    {
        float4 n = noise4(base + 512u, c);
        float4 o;
        o.x = fmaf(a2.x, scale, n.x); o.y = fmaf(a2.y, scale, n.y);
        o.z = fmaf(a2.z, scale, n.z); o.w = fmaf(a2.w, scale, n.w);
        outR[lane + 128] = o;
    }
    {
        float4 n = noise4(base + 768u, c);
        float4 o;
        o.x = fmaf(a3.x, scale, n.x); o.y = fmaf(a3.y, scale, n.y);
        o.z = fmaf(a3.z, scale, n.z); o.w = fmaf(a3.w, scale, n.w);
        outR[lane + 192] = o;
    }
}

extern "C" void kernel_launch(void* const* d_in, const int* in_sizes, int n_in,
                              void* d_out, int out_size, void* d_ws, size_t ws_size,
                              hipStream_t stream) {
    const float* in = (const float*)d_in[0];
    float* out = (float*)d_out;
    gaussian_dp_kernel<<<ROWS / 4, 256, 0, stream>>>(in, out);
}

// Round 6
// 40.997 us; speedup vs baseline: 1.8738x; 1.0395x over previous
//
#include <hip/hip_runtime.h>
#include <cstdint>
#include <cstddef>

#define ROWS 16384
#define COLS 1024

// rotl via single v_alignbit_b32: alignbit(x,x,32-r) = (x>>(32-r))|(x<<r)
__device__ __forceinline__ uint32_t rotl32(uint32_t x, int r) {
    return __builtin_amdgcn_alignbit(x, x, 32 - r);
}

__device__ __forceinline__ void tf_round(uint32_t& x0, uint32_t& x1, int r) {
    x0 += x1;
    x1 = rotl32(x1, r);
    x1 ^= x0;
}

// Threefry-2x32-20, key (0,42) == jax.random.key(42), counter (0, i),
// specialized for c0 == 0 (partitionable threefry, bits = o0 ^ o1).
__device__ __forceinline__ uint32_t threefry_bits(uint32_t i) {
    const uint32_t ks1 = 42u;
    const uint32_t ks2 = 0x1BD11BF0u;   // 0x1BD11BDA ^ 0 ^ 42

    uint32_t x1 = i + 42u;
    uint32_t x0 = x1;                    // R1: x0 = 0 + x1
    x1 = rotl32(x1, 13) ^ x0;
    tf_round(x0, x1, 15); tf_round(x0, x1, 26); tf_round(x0, x1, 6);
    x0 += ks1; x1 += ks2 + 1u;
    tf_round(x0, x1, 17); tf_round(x0, x1, 29); tf_round(x0, x1, 16); tf_round(x0, x1, 24);
    x0 += ks2; x1 += 2u;                 // ks0 == 0
    tf_round(x0, x1, 13); tf_round(x0, x1, 15); tf_round(x0, x1, 26); tf_round(x0, x1, 6);
    /* x0 += 0 */ x1 += ks1 + 3u;
    tf_round(x0, x1, 17); tf_round(x0, x1, 29); tf_round(x0, x1, 16); tf_round(x0, x1, 24);
    x0 += ks1; x1 += ks2 + 4u;
    tf_round(x0, x1, 13); tf_round(x0, x1, 15); tf_round(x0, x1, 26); tf_round(x0, x1, 6);
    x0 += ks2; x1 += 5u;                 // ks0 == 0
    return x0 ^ x1;
}

// bits -> jax uniform(-0.99999994, 1) -> 1.1*sqrt(2)*erfinv.
// v = fma(cvt(bits>>9), 2^-22, minval) is bit-identical to JAX's
// bitcast-and-subtract path: the product is exact (23-bit int, pow2 scale),
// leaving the same single rounding as fma(u, 2.0, minval).
// Central erfinv: Giles poly pre-scaled by 1.1*sqrt2 AND re-parameterized in
// y = log2(1-v^2) + 2.5/ln2  (z = w-2.5 = -ln2*y; coeffs absorb (-ln2)^j).
// High-order terms k0..k3 dropped: max added error ~2.4e-3 vs 0.12 budget.
__device__ __forceinline__ float bits_to_noise(uint32_t bits) {
    float fm = (float)(bits >> 9);                       // exact
    float v  = fmaf(fm, 2.3841858e-07f, -0.99999994f);   // 2^-22, >= minval always
    float t  = fmaf(-v, v, 1.0f);                        // 1 - v^2
    float y  = __log2f(t) + 3.6067376f;                  // + 2.5/ln2

    float p;
    p = fmaf(7.84913e-05f, y, 6.49511e-04f);
    p = fmaf(p, y, -3.12243e-03f);
    p = fmaf(p, y, -2.6594862e-01f);
    p = fmaf(p, y, 2.3356449e+00f);

    if (y <= -3.6067376f) {                              // w >= 5: ~0.33%/lane
        float w = fmaf(-0.69314718f, y, 2.5f);
        float s = __builtin_amdgcn_sqrtf(w) - 3.0f;
        float q = -3.1146030e-04f;
        q = fmaf(q, s, 1.5704224e-04f);
        q = fmaf(q, s, 2.0990855e-03f);
        q = fmaf(q, s, -5.7144932e-03f);
        q = fmaf(q, s, 8.9285939e-03f);
        q = fmaf(q, s, -1.1857797e-02f);
        q = fmaf(q, s, 1.4683435e-02f);
        q = fmaf(q, s, 1.5582439e+00f);
        q = fmaf(q, s, 4.4070777e+00f);
        p = q;
    }
    return p * v;                                        // 1.1*sqrt2*erfinv(v)
}

__device__ __forceinline__ float4 noise4(uint32_t idx0) {
    float4 n;
    n.x = bits_to_noise(threefry_bits(idx0 + 0u));
    n.y = bits_to_noise(threefry_bits(idx0 + 1u));
    n.z = bits_to_noise(threefry_bits(idx0 + 2u));
    n.w = bits_to_noise(threefry_bits(idx0 + 3u));
    return n;
}

__device__ __forceinline__ float ssq4(float4 a) {
    return fmaf(a.x, a.x, fmaf(a.y, a.y, fmaf(a.z, a.z, a.w * a.w)));
}

// One WAVE per row (64 lanes x 16 elems); 4 rows per 256-thread block.
// Order: issue loads -> compute ALL noise (load-independent, ~1400 VALU
// instrs hide the ~900cy HBM latency) -> ssq/reduce/scale -> fuse -> store.
__global__ void __launch_bounds__(256)
gaussian_dp_kernel(const float* __restrict__ in, float* __restrict__ out) {
    const int wid  = threadIdx.x >> 6;
    const int lane = threadIdx.x & 63;
    const int r    = (blockIdx.x << 2) + wid;   // 0..16383

    const float4* inR = reinterpret_cast<const float4*>(in + (size_t)r * COLS);
    float4 a0 = inR[lane];
    float4 a1 = inR[lane + 64];
    float4 a2 = inR[lane + 128];
    float4 a3 = inR[lane + 192];

    const uint32_t base = ((uint32_t)r << 10) + ((uint32_t)lane << 2);

    // noise first — no dependence on the loads above
    float4 n0 = noise4(base);
    float4 n1 = noise4(base + 256u);
    float4 n2 = noise4(base + 512u);
    float4 n3 = noise4(base + 768u);

    float ssq = (ssq4(a0) + ssq4(a1)) + (ssq4(a2) + ssq4(a3));

    #pragma unroll
    for (int off = 32; off > 0; off >>= 1) {
        ssq += __shfl_xor(ssq, off, 64);
    }

    const float scale = 1.0f / fmaxf(__builtin_amdgcn_sqrtf(ssq), 1.0f);

    float4* outR = reinterpret_cast<float4*>(out + (size_t)r * COLS);

    float4 o;
    o.x = fmaf(a0.x, scale, n0.x); o.y = fmaf(a0.y, scale, n0.y);
    o.z = fmaf(a0.z, scale, n0.z); o.w = fmaf(a0.w, scale, n0.w);
    outR[lane] = o;

    o.x = fmaf(a1.x, scale, n1.x); o.y = fmaf(a1.y, scale, n1.y);
    o.z = fmaf(a1.z, scale, n1.z); o.w = fmaf(a1.w, scale, n1.w);
    outR[lane + 64] = o;

    o.x = fmaf(a2.x, scale, n2.x); o.y = fmaf(a2.y, scale, n2.y);
    o.z = fmaf(a2.z, scale, n2.z); o.w = fmaf(a2.w, scale, n2.w);
    outR[lane + 128] = o;

    o.x = fmaf(a3.x, scale, n3.x); o.y = fmaf(a3.y, scale, n3.y);
    o.z = fmaf(a3.z, scale, n3.z); o.w = fmaf(a3.w, scale, n3.w);
    outR[lane + 192] = o;
}

extern "C" void kernel_launch(void* const* d_in, const int* in_sizes, int n_in,
                              void* d_out, int out_size, void* d_ws, size_t ws_size,
                              hipStream_t stream) {
    const float* in = (const float*)d_in[0];
    float* out = (float*)d_out;
    gaussian_dp_kernel<<<ROWS / 4, 256, 0, stream>>>(in, out);
}

// Round 7
// 40.504 us; speedup vs baseline: 1.8967x; 1.0122x over previous
//
#include <hip/hip_runtime.h>
#include <cstdint>
#include <cstddef>

#define ROWS 16384
#define COLS 1024

// rotl via single v_alignbit_b32: alignbit(x,x,32-r) = (x>>(32-r))|(x<<r)
__device__ __forceinline__ uint32_t rotl32(uint32_t x, int r) {
    return __builtin_amdgcn_alignbit(x, x, 32 - r);
}

// Four Threefry-2x32 states advanced in lockstep: every stage is 4
// independent ops, so the ~4-cycle dep latency is hidden at 2-cycle issue.
struct TF4 { uint32_t a0,a1,b0,b1,c0,c1,d0,d1; };

__device__ __forceinline__ void tf_round4(TF4& s, int r) {
    s.a0 += s.a1; s.b0 += s.b1; s.c0 += s.c1; s.d0 += s.d1;
    s.a1 = rotl32(s.a1, r) ^ s.a0;
    s.b1 = rotl32(s.b1, r) ^ s.b0;
    s.c1 = rotl32(s.c1, r) ^ s.c0;
    s.d1 = rotl32(s.d1, r) ^ s.d0;
}

__device__ __forceinline__ void inj4(TF4& s, uint32_t k0, uint32_t k1) {
    s.a0 += k0; s.b0 += k0; s.c0 += k0; s.d0 += k0;
    s.a1 += k1; s.b1 += k1; s.c1 += k1; s.d1 += k1;
}

__device__ __forceinline__ void inj4_x1(TF4& s, uint32_t k1) {  // x0 += 0
    s.a1 += k1; s.b1 += k1; s.c1 += k1; s.d1 += k1;
}

// Threefry-2x32-20, key (0,42), counters (0, i..i+3), bits = o0 ^ o1.
__device__ __forceinline__ uint4 threefry_bits4(uint32_t i) {
    const uint32_t ks1 = 42u;
    const uint32_t ks2 = 0x1BD11BF0u;   // 0x1BD11BDA ^ 0 ^ 42

    TF4 s;
    s.a1 = i + 42u;  s.a0 = s.a1;       // x0 = 0 + x1 after round-1 add
    s.b1 = i + 43u;  s.b0 = s.b1;
    s.c1 = i + 44u;  s.c0 = s.c1;
    s.d1 = i + 45u;  s.d0 = s.d1;
    s.a1 = rotl32(s.a1, 13) ^ s.a0;     // round-1 tail
    s.b1 = rotl32(s.b1, 13) ^ s.b0;
    s.c1 = rotl32(s.c1, 13) ^ s.c0;
    s.d1 = rotl32(s.d1, 13) ^ s.d0;
    tf_round4(s, 15); tf_round4(s, 26); tf_round4(s, 6);
    inj4(s, ks1, ks2 + 1u);
    tf_round4(s, 17); tf_round4(s, 29); tf_round4(s, 16); tf_round4(s, 24);
    inj4(s, ks2, 2u);                   // ks0 == 0
    tf_round4(s, 13); tf_round4(s, 15); tf_round4(s, 26); tf_round4(s, 6);
    inj4_x1(s, ks1 + 3u);               // x0 += 0
    tf_round4(s, 17); tf_round4(s, 29); tf_round4(s, 16); tf_round4(s, 24);
    inj4(s, ks1, ks2 + 4u);
    tf_round4(s, 13); tf_round4(s, 15); tf_round4(s, 26); tf_round4(s, 6);
    inj4(s, ks2, 5u);                   // ks0 == 0

    return make_uint4(s.a0 ^ s.a1, s.b0 ^ s.b1, s.c0 ^ s.c1, s.d0 ^ s.d1);
}

// Rare tail (w >= 5, ~0.33%/lane): full-accuracy Giles upper branch,
// coefficients pre-scaled by 1.1*sqrt(2).
__device__ __noinline__ float noise_tail(float y) {
    float w = fmaf(-0.69314718f, y, 2.5f);
    float s = __builtin_amdgcn_sqrtf(w) - 3.0f;
    float q = -3.1146030e-04f;
    q = fmaf(q, s, 1.5704224e-04f);
    q = fmaf(q, s, 2.0990855e-03f);
    q = fmaf(q, s, -5.7144932e-03f);
    q = fmaf(q, s, 8.9285939e-03f);
    q = fmaf(q, s, -1.1857797e-02f);
    q = fmaf(q, s, 1.4683435e-02f);
    q = fmaf(q, s, 1.5582439e+00f);
    q = fmaf(q, s, 4.4070777e+00f);
    return q;
}

// 4 elements, stage-interleaved (SoA) so the float dep chains also overlap.
// v = fma(cvt(bits>>9), 2^-22, minval) is bit-identical to JAX's path.
// Central poly: Giles coeffs pre-scaled by 1.1*sqrt2, re-parameterized in
// y = log2(1-v^2) + 2.5/ln2; k0..k3 dropped (adds <=2.4e-3 vs 0.12 budget).
__device__ __forceinline__ float4 noise4(uint32_t idx0) {
    uint4 b = threefry_bits4(idx0);

    float f0 = (float)(b.x >> 9);
    float f1 = (float)(b.y >> 9);
    float f2 = (float)(b.z >> 9);
    float f3 = (float)(b.w >> 9);

    const float S = 2.3841858e-07f;      // 2^-22
    const float M = -0.99999994f;
    float v0 = fmaf(f0, S, M), v1 = fmaf(f1, S, M),
          v2 = fmaf(f2, S, M), v3 = fmaf(f3, S, M);

    float t0 = fmaf(-v0, v0, 1.0f), t1 = fmaf(-v1, v1, 1.0f),
          t2 = fmaf(-v2, v2, 1.0f), t3 = fmaf(-v3, v3, 1.0f);

    const float C = 3.6067376f;          // 2.5/ln2
    float y0 = __log2f(t0) + C, y1 = __log2f(t1) + C,
          y2 = __log2f(t2) + C, y3 = __log2f(t3) + C;

    const float K4 = 7.84913e-05f, K3 = 6.49511e-04f, K2 = -3.12243e-03f,
                K1 = -2.6594862e-01f, K0 = 2.3356449e+00f;
    float p0 = fmaf(K4, y0, K3), p1 = fmaf(K4, y1, K3),
          p2 = fmaf(K4, y2, K3), p3 = fmaf(K4, y3, K3);
    p0 = fmaf(p0, y0, K2); p1 = fmaf(p1, y1, K2);
    p2 = fmaf(p2, y2, K2); p3 = fmaf(p3, y3, K2);
    p0 = fmaf(p0, y0, K1); p1 = fmaf(p1, y1, K1);
    p2 = fmaf(p2, y2, K1); p3 = fmaf(p3, y3, K1);
    p0 = fmaf(p0, y0, K0); p1 = fmaf(p1, y1, K0);
    p2 = fmaf(p2, y2, K0); p3 = fmaf(p3, y3, K0);

    if (y0 <= -3.6067376f) p0 = noise_tail(y0);
    if (y1 <= -3.6067376f) p1 = noise_tail(y1);
    if (y2 <= -3.6067376f) p2 = noise_tail(y2);
    if (y3 <= -3.6067376f) p3 = noise_tail(y3);

    float4 n;
    n.x = p0 * v0; n.y = p1 * v1; n.z = p2 * v2; n.w = p3 * v3;
    return n;
}

__device__ __forceinline__ float ssq4(float4 a) {
    return fmaf(a.x, a.x, fmaf(a.y, a.y, fmaf(a.z, a.z, a.w * a.w)));
}

// One WAVE per row (64 lanes x 16 elems); 4 rows per 256-thread block.
// Order: issue loads -> all noise (load-independent) -> reduce -> fuse.
__global__ void __launch_bounds__(256)
gaussian_dp_kernel(const float* __restrict__ in, float* __restrict__ out) {
    const int wid  = threadIdx.x >> 6;
    const int lane = threadIdx.x & 63;
    const int r    = (blockIdx.x << 2) + wid;   // 0..16383

    const float4* inR = reinterpret_cast<const float4*>(in + (size_t)r * COLS);
    float4 a0 = inR[lane];
    float4 a1 = inR[lane + 64];
    float4 a2 = inR[lane + 128];
    float4 a3 = inR[lane + 192];

    const uint32_t base = ((uint32_t)r << 10) + ((uint32_t)lane << 2);

    float4 n0 = noise4(base);
    float4 n1 = noise4(base + 256u);
    float4 n2 = noise4(base + 512u);
    float4 n3 = noise4(base + 768u);

    float ssq = (ssq4(a0) + ssq4(a1)) + (ssq4(a2) + ssq4(a3));

    #pragma unroll
    for (int off = 32; off > 0; off >>= 1) {
        ssq += __shfl_xor(ssq, off, 64);
    }

    const float scale = 1.0f / fmaxf(__builtin_amdgcn_sqrtf(ssq), 1.0f);

    float4* outR = reinterpret_cast<float4*>(out + (size_t)r * COLS);

    float4 o;
    o.x = fmaf(a0.x, scale, n0.x); o.y = fmaf(a0.y, scale, n0.y);
    o.z = fmaf(a0.z, scale, n0.z); o.w = fmaf(a0.w, scale, n0.w);
    outR[lane] = o;

    o.x = fmaf(a1.x, scale, n1.x); o.y = fmaf(a1.y, scale, n1.y);
    o.z = fmaf(a1.z, scale, n1.z); o.w = fmaf(a1.w, scale, n1.w);
    outR[lane + 64] = o;

    o.x = fmaf(a2.x, scale, n2.x); o.y = fmaf(a2.y, scale, n2.y);
    o.z = fmaf(a2.z, scale, n2.z); o.w = fmaf(a2.w, scale, n2.w);
    outR[lane + 128] = o;

    o.x = fmaf(a3.x, scale, n3.x); o.y = fmaf(a3.y, scale, n3.y);
    o.z = fmaf(a3.z, scale, n3.z); o.w = fmaf(a3.w, scale, n3.w);
    outR[lane + 192] = o;
}

extern "C" void kernel_launch(void* const* d_in, const int* in_sizes, int n_in,
                              void* d_out, int out_size, void* d_ws, size_t ws_size,
                              hipStream_t stream) {
    const float* in = (const float*)d_in[0];
    float* out = (float*)d_out;
    gaussian_dp_kernel<<<ROWS / 4, 256, 0, stream>>>(in, out);
}